// Round 1
// baseline (1576.780 us; speedup 1.0000x reference)
//
#include <hip/hip_runtime.h>
#include <stdint.h>

#define B_  2
#define H_  4
#define T_  2048
#define N_  4096
#define BH  8          // B_*H_

#define BM 128
#define BN 128
#define BK 64

typedef __attribute__((ext_vector_type(8))) short  short8;
typedef __attribute__((ext_vector_type(4))) float  floatx4;

// ---- helpers ---------------------------------------------------------------

__device__ __forceinline__ unsigned short f2bf(float x) {
  union { float f; unsigned u; } un; un.f = x;
  unsigned r = un.u + 0x7FFFu + ((un.u >> 16) & 1u);   // round-to-nearest-even
  return (unsigned short)(r >> 16);
}

__device__ __forceinline__ void async_copy16(const void* g, void* l) {
  __builtin_amdgcn_global_load_lds(
      (const __attribute__((address_space(1))) unsigned int*)g,
      (__attribute__((address_space(3))) unsigned int*)l,
      16, 0, 0);
}

// ---- kernel 1: RoPE(Q) + cast to bf16 --------------------------------------
// layout [b][h][t][n]; freq(n) = 2^(-(n&~1)/256) / (2*pi); phase = t*freq mod 1
// out[2j]   = q[2j]*cos - q[2j+1]*sin ; out[2j+1] = q[2j+1]*cos + q[2j]*sin
__global__ __launch_bounds__(256)
void rope_cast_kernel(const float* __restrict__ Q, unsigned short* __restrict__ QR) {
  const long e0 = ((long)blockIdx.x * 256 + threadIdx.x) * 8;
  const float4 v0 = *(const float4*)(Q + e0);
  const float4 v1 = *(const float4*)(Q + e0 + 4);
  const int   n0 = (int)(e0 & (N_ - 1));
  const float t  = (float)((int)((e0 >> 12) & (T_ - 1)));
  float vv[8] = {v0.x, v0.y, v0.z, v0.w, v1.x, v1.y, v1.z, v1.w};
  union { short8 v; unsigned short u[8]; } o;
#pragma unroll
  for (int p = 0; p < 4; ++p) {
    const int n = n0 + 2 * p;                       // even (n0 is multiple of 8)
    // freq in "revolutions per step": 2^(-n/256) * 1/(2*pi)
    const float freq = exp2f(-(float)n * (1.0f / 256.0f)) * 0.15915494309189535f;
    const float ph = t * freq;
    const float fr = ph - floorf(ph);               // phases % 1.0
    // v_sin/v_cos take revolutions: sin(2*pi*fr), cos(2*pi*fr)
    const float s = __builtin_amdgcn_sinf(fr);
    const float c = __builtin_amdgcn_cosf(fr);
    o.u[2 * p]     = f2bf(vv[2 * p] * c - vv[2 * p + 1] * s);
    o.u[2 * p + 1] = f2bf(vv[2 * p + 1] * c + vv[2 * p] * s);
  }
  *(short8*)(QR + e0) = o.v;
}

// ---- kernel 2: transpose + cast V -> Vt (bf16), per (b,h): Vt[n][s]=V[s][n] -
__global__ __launch_bounds__(256)
void transpose_cast_kernel(const float* __restrict__ V, unsigned short* __restrict__ Vt) {
  __shared__ float tile[64][65];                    // +1 pad: conflict-free transpose
  const long bh = blockIdx.z;
  const float* Vb = V + bh * (long)T_ * N_;
  unsigned short* Vtb = Vt + bh * (long)N_ * T_;
  const int s0 = blockIdx.x * 64;
  const int n0 = blockIdx.y * 64;
  const int tx = threadIdx.x & 63;
  const int ty = threadIdx.x >> 6;                  // 0..3
#pragma unroll
  for (int i = 0; i < 16; ++i) {
    const int r = ty * 16 + i;
    tile[r][tx] = Vb[(long)(s0 + r) * N_ + n0 + tx];  // coalesced read
  }
  __syncthreads();
#pragma unroll
  for (int i = 0; i < 16; ++i) {
    const int r = ty * 16 + i;                      // n index
    Vtb[(long)(n0 + r) * T_ + s0 + tx] = f2bf(tile[tx][r]);  // coalesced write
  }
}

// ---- m97-style bf16 GEMM (B^T layout): C[m][n] = alpha * sum_k A[m][k]B[n][k]
// A: [M x K] bf16 row-major, B: [Nc x K] bf16 row-major, per-bh strides.
template <typename OutT>
__global__ __launch_bounds__(256)
void gemm_bt(const unsigned short* __restrict__ A, const unsigned short* __restrict__ B,
             OutT* __restrict__ C, int M, int Nc, int K, float alpha,
             long sA, long sB, long sC)
{
  __shared__ unsigned short As[BM * BK];            // 16 KB, lane-linear (no pad!)
  __shared__ unsigned short Bs[BN * BK];            // 16 KB

  const int tid  = threadIdx.x;
  const int lane = tid & 63;
  const int wave = tid >> 6;

  const long bh = blockIdx.z;
  const unsigned short* Ab = A + bh * sA;
  const unsigned short* Bb = B + bh * sB;
  OutT* Cb = C + bh * sC;

  const int tM = blockIdx.y * BM;
  const int tN = blockIdx.x * BN;

  const int wm = (wave >> 1) * 64;                  // wave's 64x64 sub-tile
  const int wn = (wave & 1) * 64;

  const int srow = tid >> 3;                        // staging: 0..31
  const int scol = (tid & 7) * 8;                   // 0,8,..,56

  const int lr = lane & 15;                         // fragment row/col
  const int lk = (lane >> 4) * 8;                   // fragment k offset

  floatx4 acc[4][4] = {};

  for (int k0 = 0; k0 < K; k0 += BK) {
    const unsigned short* ga = Ab + (long)(tM + srow) * K + (k0 + scol);
    const unsigned short* gb = Bb + (long)(tN + srow) * K + (k0 + scol);
#pragma unroll
    for (int i = 0; i < 4; ++i) {
      // wave-uniform LDS base; HW scatters lane L to base + L*16B
      async_copy16(ga + (long)(i * 32) * K, &As[i * 2048 + wave * 512]);
      async_copy16(gb + (long)(i * 32) * K, &Bs[i * 2048 + wave * 512]);
    }
    __syncthreads();
#pragma unroll
    for (int kk = 0; kk < BK; kk += 32) {
      short8 af[4], bf[4];
#pragma unroll
      for (int i = 0; i < 4; ++i)
        af[i] = *(const short8*)&As[(wm + i * 16 + lr) * BK + kk + lk];
#pragma unroll
      for (int j = 0; j < 4; ++j)
        bf[j] = *(const short8*)&Bs[(wn + j * 16 + lr) * BK + kk + lk];
#pragma unroll
      for (int i = 0; i < 4; ++i)
#pragma unroll
        for (int j = 0; j < 4; ++j)
          acc[i][j] = __builtin_amdgcn_mfma_f32_16x16x32_bf16(af[i], bf[j], acc[i][j], 0, 0, 0);
    }
    __syncthreads();
  }

  // epilogue: D mapping col = lane&15, row = (lane>>4)*4 + r
  const int crow = (lane >> 4) * 4;
  const int ccol = lane & 15;
#pragma unroll
  for (int i = 0; i < 4; ++i)
#pragma unroll
    for (int j = 0; j < 4; ++j)
#pragma unroll
      for (int r = 0; r < 4; ++r) {
        const long row = tM + wm + i * 16 + crow + r;
        const long col = tN + wn + j * 16 + ccol;
        const float v = acc[i][j][r] * alpha;
        OutT* p = &Cb[row * (long)Nc + col];
        if constexpr (sizeof(OutT) == 2) *p = (OutT)f2bf(v);
        else                             *p = (OutT)v;
      }
}

// ---- launch ----------------------------------------------------------------
extern "C" void kernel_launch(void* const* d_in, const int* in_sizes, int n_in,
                              void* d_out, int out_size, void* d_ws, size_t ws_size,
                              hipStream_t stream) {
  const float* Q = (const float*)d_in[0];
  // d_in[1] (K) is unused by the reference.
  const float* V = (const float*)d_in[2];
  float* O = (float*)d_out;

  // workspace layout: QRb (134MB) | Vtb (134MB) | S (64MB)  => ~320 MiB
  unsigned short* QRb = (unsigned short*)d_ws;
  unsigned short* Vtb = QRb + (size_t)BH * T_ * N_;
  unsigned short* S   = Vtb + (size_t)BH * T_ * N_;

  // 1. RoPE(Q) -> bf16
  rope_cast_kernel<<<(BH * (long)T_ * N_) / (8 * 256), 256, 0, stream>>>(Q, QRb);
  // 2. V -> Vt (bf16)
  transpose_cast_kernel<<<dim3(T_ / 64, N_ / 64, BH), 256, 0, stream>>>(V, Vtb);
  // 3. S = (1/64) * QR @ QR^T   [per bh: 2048x2048, K=4096]
  gemm_bt<unsigned short><<<dim3(T_ / BN, T_ / BM, BH), 256, 0, stream>>>(
      QRb, QRb, S, T_, T_, N_, 1.0f / 64.0f,
      (long)T_ * N_, (long)T_ * N_, (long)T_ * T_);
  // 4. O = S @ Vt^T             [per bh: 2048x4096, K=2048]
  gemm_bt<float><<<dim3(N_ / BN, T_ / BM, BH), 256, 0, stream>>>(
      S, Vtb, O, T_, N_, T_, 1.0f,
      (long)T_ * T_, (long)N_ * T_, (long)T_ * N_);
}